// Round 12
// baseline (280.430 us; speedup 1.0000x reference)
//
#include <hip/hip_runtime.h>

// ===== R12: read-bandwidth probe round =====
// Every structure R1-R11 converges to ~3.2-4.0 TB/s effective X-stream rate;
// write BW is proven 6.5+ TB/s (fills) but sequential READ BW on this buffer
// has never been measured. This round inserts a pure float4 read-sum probe
// (the 6.3 TB/s ubench pattern) between pack_weights and the known-good R8
// kernel. probe_time = dur_us - 178us. Decides MFMA-rewrite vs roofline-stop.

constexpr int POS = 63;
constexpr int LAT = 256;
constexpr int DIM = 319;
constexpr int NCH = 192;                       // 3 * 64 clusters
constexpr int PW_DWORDS = NCH * 192;           // 36864
constexpr size_t PW_BYTES = (size_t)PW_DWORDS * 4;   // 147,456 (16-aligned)
constexpr int PROBE_BLOCKS = 2048;
constexpr size_t SINK_BYTES = (size_t)PROBE_BLOCKS * 256 * 4;  // 2 MB

// ---------- RNE float -> bf16 bits ----------
__device__ __forceinline__ unsigned f2bf(float f) {
    unsigned u = __float_as_uint(f);
    return (u + 0x7fffu + ((u >> 16) & 1u)) >> 16;
}

// ---------- pack weights (R8 layout) ----------
// pw[ch*192 + d*64 + l] = bf16(w[ch][l+128d]) | bf16(w[ch][l+64+128d])<<16
__global__ __launch_bounds__(256) void pack_weights(
    const float* __restrict__ Wp,   // [192, 63]
    const float* __restrict__ Wf,   // [192, 256]
    unsigned* __restrict__ pw)
{
    const int idx = blockIdx.x * 256 + threadIdx.x;
    if (idx >= PW_DWORDS) return;
    const int ch  = idx / 192;
    const int rem = idx - ch * 192;
    const int d   = rem >> 6;
    const int l   = rem & 63;
    const int klo = l + 128 * d;
    const int khi = klo + 64;
    auto wat = [&](int k) -> float {
        if (k < POS) return Wp[ch * POS + k];
        if (k < DIM) return Wf[ch * LAT + (k - POS)];
        return 0.f;
    };
    pw[idx] = f2bf(wat(klo)) | (f2bf(wat(khi)) << 16);
}

// ---------- pure sequential read probe: float4 grid-stride sum ----------
__global__ __launch_bounds__(256) void read_probe(
    const float4* __restrict__ X4, long nf4, float* __restrict__ sink)
{
    const long tid = (long)blockIdx.x * 256 + threadIdx.x;
    const long stride = (long)PROBE_BLOCKS * 256;
    float acc = 0.f;
    for (long i = tid; i < nf4; i += stride) {
        const float4 v = X4[i];
        acc += v.x + v.y + v.z + v.w;
    }
    sink[tid] = acc;   // deterministic, prevents DCE
}

// ---------- DPP wave64 sum (pure VALU), result valid in lane 63 ----------
template <int CTRL>
__device__ __forceinline__ float dpp_add_step(float x) {
    int s = __builtin_amdgcn_update_dpp(0, __float_as_int(x), CTRL,
                                        0xF, 0xF, /*bound_ctrl=*/true);
    return x + __int_as_float(s);
}
__device__ __forceinline__ float wave_reduce_sum(float x) {
    x = dpp_add_step<0x111>(x);  // row_shr:1
    x = dpp_add_step<0x112>(x);  // row_shr:2
    x = dpp_add_step<0x114>(x);  // row_shr:4
    x = dpp_add_step<0x118>(x);  // row_shr:8
    x = dpp_add_step<0x142>(x);  // row_bcast15
    x = dpp_add_step<0x143>(x);  // row_bcast31
    return x;                    // lane 63
}

__device__ __forceinline__ float blo(unsigned w) { return __uint_as_float(w << 16); }
__device__ __forceinline__ float bhi(unsigned w) { return __uint_as_float(w & 0xffff0000u); }

// ---------- main (R8 verbatim): one wave per row, sequential order ----------
__global__ __launch_bounds__(256) void lad_seq(
    const float* __restrict__ X,
    const int*   __restrict__ cid,
    const unsigned* __restrict__ pw,
    float*       __restrict__ out,
    int n)
{
    const int l    = threadIdx.x & 63;
    const int wave = (int)((blockIdx.x * blockDim.x + threadIdx.x) >> 6);
    if (wave >= n) return;

    const size_t row = (size_t)wave;
    const float* xr = X + row * (size_t)DIM;
    const int c3 = 3 * __builtin_amdgcn_readfirstlane(cid[row]);
    const unsigned* wb = pw + (size_t)c3 * 192;

    const float x0 = xr[l];
    const float x1 = xr[l + 64];
    const float x2 = xr[l + 128];
    const float x3 = xr[l + 192];
    const float x4 = (l < 63) ? xr[l + 256] : 0.f;

    const unsigned wA0 = wb[l],       wA1 = wb[64 + l],  wA2 = wb[128 + l];
    const unsigned wB0 = wb[192 + l], wB1 = wb[256 + l], wB2 = wb[320 + l];
    const unsigned wC0 = wb[384 + l], wC1 = wb[448 + l], wC2 = wb[512 + l];

    float a0 = x0 * blo(wA0);
    a0 = fmaf(x1, bhi(wA0), a0);
    a0 = fmaf(x2, blo(wA1), a0);
    a0 = fmaf(x3, bhi(wA1), a0);
    a0 = fmaf(x4, blo(wA2), a0);

    float a1 = x0 * blo(wB0);
    a1 = fmaf(x1, bhi(wB0), a1);
    a1 = fmaf(x2, blo(wB1), a1);
    a1 = fmaf(x3, bhi(wB1), a1);
    a1 = fmaf(x4, blo(wB2), a1);

    float a2 = x0 * blo(wC0);
    a2 = fmaf(x1, bhi(wC0), a2);
    a2 = fmaf(x2, blo(wC1), a2);
    a2 = fmaf(x3, bhi(wC1), a2);
    a2 = fmaf(x4, blo(wC2), a2);

    a0 = wave_reduce_sum(a0);
    a1 = wave_reduce_sum(a1);
    a2 = wave_reduce_sum(a2);

    if (l == 63) {
        float* o = out + row * 3;
        o[0] = a0; o[1] = a1; o[2] = a2;
    }
}

// ---------- fallback (fp32 weights) if workspace too small ----------
__global__ __launch_bounds__(256) void lad_fallback(
    const float* __restrict__ X,
    const int*   __restrict__ cid,
    const float* __restrict__ Wp,
    const float* __restrict__ Wf,
    float*       __restrict__ out,
    int n)
{
    const int lane = threadIdx.x & 63;
    const int wave = (int)((blockIdx.x * blockDim.x + threadIdx.x) >> 6);
    if (wave >= n) return;
    const size_t row = (size_t)wave;
    const float* xrow = X + row * (size_t)DIM;
    const float* xf   = xrow + POS;
    const int c3 = cid[row] * 3;
    const float* wp0 = Wp + (size_t)c3 * POS;
    const float* wf0 = Wf + (size_t)c3 * LAT;
    float a0 = 0.f, a1 = 0.f, a2 = 0.f;
#pragma unroll
    for (int i = 0; i < 4; ++i) {
        const int k = lane + 64 * i;
        const float x = xf[k];
        a0 = fmaf(x, wf0[k], a0);
        a1 = fmaf(x, wf0[k + LAT], a1);
        a2 = fmaf(x, wf0[k + 2 * LAT], a2);
    }
    if (lane < POS) {
        const float x = xrow[lane];
        a0 = fmaf(x, wp0[lane], a0);
        a1 = fmaf(x, wp0[lane + POS], a1);
        a2 = fmaf(x, wp0[lane + 2 * POS], a2);
    }
    a0 = wave_reduce_sum(a0);
    a1 = wave_reduce_sum(a1);
    a2 = wave_reduce_sum(a2);
    if (lane == 63) {
        float* o = out + row * 3;
        o[0] = a0; o[1] = a1; o[2] = a2;
    }
}

extern "C" void kernel_launch(void* const* d_in, const int* in_sizes, int n_in,
                              void* d_out, int out_size, void* d_ws, size_t ws_size,
                              hipStream_t stream) {
    const float* X   = (const float*)d_in[0];
    const int*   cid = (const int*)d_in[1];
    const float* Wp  = (const float*)d_in[2];
    const float* Wf  = (const float*)d_in[3];
    float* out = (float*)d_out;
    const int n = in_sizes[1];

    if (ws_size >= PW_BYTES + SINK_BYTES) {
        unsigned* pw = (unsigned*)d_ws;
        float* sink  = (float*)((char*)d_ws + PW_BYTES);

        pack_weights<<<(PW_DWORDS + 255) / 256, 256, 0, stream>>>(Wp, Wf, pw);

        // Probe: pure sequential float4 read of all of X.
        const long nf4 = (long)n * DIM / 4;
        read_probe<<<PROBE_BLOCKS, 256, 0, stream>>>(
            (const float4*)X, nf4, sink);

        const int blocks = (n + 3) / 4;
        lad_seq<<<blocks, 256, 0, stream>>>(X, cid, pw, out, n);
    } else {
        const int blocks = (n + 3) / 4;
        lad_fallback<<<blocks, 256, 0, stream>>>(X, cid, Wp, Wf, out, n);
    }
}

// Round 13
// 232.636 us; speedup vs baseline: 1.2054x; 1.2054x over previous
//
#include <hip/hip_runtime.h>

// LinearAutoDecoder R13: float4 X loads (probe-proven 6.5 TB/s pattern) +
// delta-shifted bf16 weight tables + minimal R8 compute structure.
// R12 probe: pure float4 grid-stride read of X = ~102us (6.55 TB/s); every
// dword-X compute kernel = 3.2-4.0 TB/s. Fix: load each 319-float row as 81
// ALIGNED float4 slots starting at S=(319r-delta)/4, delta=(3r)&3; weight
// table tb[delta][ch][slot] holds bf16 w[4*slot+e-delta] (zero outside row)
// so foreign elements multiply by 0. Per row: 2 f4 X loads, 6 dwordx2 W
// loads, 18-DPP reduce, 12B write.

constexpr int POS = 63;
constexpr int LAT = 256;
constexpr int DIM = 319;
constexpr int NCH = 192;                   // 3 * 64 clusters
constexpr int TSLOTS = 81;                 // float4 slots per (delta, ch)
constexpr int TB_ENTRIES = 4 * NCH * TSLOTS;          // 62208
constexpr size_t TB_BYTES = (size_t)TB_ENTRIES * 8;   // 497,664 B
constexpr int NBLK = 2048;                 // grid-stride blocks
constexpr int NWAVES = NBLK * 4;           // 8192 waves

// ---------- RNE float -> bf16 bits ----------
__device__ __forceinline__ unsigned f2bf(float f) {
    unsigned u = __float_as_uint(f);
    return (u + 0x7fffu + ((u >> 16) & 1u)) >> 16;
}

// ---------- build shifted bf16 tables ----------
// tb[((d*NCH + ch)*TSLOTS + sl)] : uint2 packing bf16 of
//   w_cat[ch][4*sl + e - d], e = 0..3 (x: e0|e1, y: e2|e3), 0 outside [0,319)
__global__ __launch_bounds__(256) void build_tab(
    const float* __restrict__ Wp,   // [192, 63]
    const float* __restrict__ Wf,   // [192, 256]
    uint2* __restrict__ tb)
{
    const int idx = blockIdx.x * 256 + threadIdx.x;
    if (idx >= TB_ENTRIES) return;
    const int sl = idx % TSLOTS;
    const int t  = idx / TSLOTS;
    const int ch = t % NCH;
    const int d  = t / NCH;
    auto wat = [&](int k) -> float {
        if (k < 0) return 0.f;
        if (k < POS) return Wp[ch * POS + k];
        if (k < DIM) return Wf[ch * LAT + (k - POS)];
        return 0.f;
    };
    unsigned b0 = f2bf(wat(4 * sl + 0 - d));
    unsigned b1 = f2bf(wat(4 * sl + 1 - d));
    unsigned b2 = f2bf(wat(4 * sl + 2 - d));
    unsigned b3 = f2bf(wat(4 * sl + 3 - d));
    tb[idx] = make_uint2(b0 | (b1 << 16), b2 | (b3 << 16));
}

// ---------- DPP wave64 sum (pure VALU), result valid in lane 63 ----------
template <int CTRL>
__device__ __forceinline__ float dpp_add_step(float x) {
    int s = __builtin_amdgcn_update_dpp(0, __float_as_int(x), CTRL,
                                        0xF, 0xF, /*bound_ctrl=*/true);
    return x + __int_as_float(s);
}
__device__ __forceinline__ float wave_reduce_sum(float x) {
    x = dpp_add_step<0x111>(x);  // row_shr:1
    x = dpp_add_step<0x112>(x);  // row_shr:2
    x = dpp_add_step<0x114>(x);  // row_shr:4
    x = dpp_add_step<0x118>(x);  // row_shr:8
    x = dpp_add_step<0x142>(x);  // row_bcast15
    x = dpp_add_step<0x143>(x);  // row_bcast31
    return x;                    // lane 63
}

__device__ __forceinline__ float blo(unsigned w) { return __uint_as_float(w << 16); }
__device__ __forceinline__ float bhi(unsigned w) { return __uint_as_float(w & 0xffff0000u); }

__device__ __forceinline__ float dot4(const float4& x, const uint2& w) {
    float a = x.x * blo(w.x);
    a = fmaf(x.y, bhi(w.x), a);
    a = fmaf(x.z, blo(w.y), a);
    a = fmaf(x.w, bhi(w.y), a);
    return a;
}

// ---------- main: one wave per row, float4 X, grid-stride ----------
__global__ __launch_bounds__(256, 6) void lad_f4(
    const float4* __restrict__ X4,
    const int*    __restrict__ cid,
    const uint2*  __restrict__ tb,
    float*        __restrict__ out,
    int n, long nf4)
{
    const int l = threadIdx.x & 63;
    const int wid = blockIdx.x * 4 + (threadIdx.x >> 6);
    const bool m2 = (l < 17);     // slots 64..80

    for (int r = wid; r < n; r += NWAVES) {
        const int c3 = 3 * __builtin_amdgcn_readfirstlane(cid[r]);
        const int del = (3 * r) & 3;                  // (319*r) & 3
        const long S4 = ((long)319 * r - del) >> 2;   // aligned float4 start

        // X: 2 coalesced float4 loads (second masked to 17 lanes, clamped).
        const float4 xA = X4[S4 + l];
        float4 xB = make_float4(0.f, 0.f, 0.f, 0.f);
        if (m2) {
            long i2 = S4 + 64 + l;
            if (i2 >= nf4) i2 = nf4 - 1;   // tail guard (weights there = 0)
            xB = X4[i2];
        }

        // W: 6 dwordx2 loads from the delta-table (coalesced, L2-hot).
        const uint2* t0 = tb + ((size_t)(del * NCH + c3) * TSLOTS);
        const uint2* t1 = t0 + TSLOTS;
        const uint2* t2 = t1 + TSLOTS;

        float a0 = dot4(xA, t0[l]);
        float a1 = dot4(xA, t1[l]);
        float a2 = dot4(xA, t2[l]);
        if (m2) {
            a0 += dot4(xB, t0[64 + l]);
            a1 += dot4(xB, t1[64 + l]);
            a2 += dot4(xB, t2[64 + l]);
        }

        a0 = wave_reduce_sum(a0);
        a1 = wave_reduce_sum(a1);
        a2 = wave_reduce_sum(a2);

        if (l == 63) {
            float* o = out + (size_t)r * 3;
            o[0] = a0; o[1] = a1; o[2] = a2;
        }
    }
}

// ---------- fallback (R2 kernel, fp32 weights) if workspace too small ------
__global__ __launch_bounds__(256) void lad_fallback(
    const float* __restrict__ X,
    const int*   __restrict__ cid,
    const float* __restrict__ Wp,
    const float* __restrict__ Wf,
    float*       __restrict__ out,
    int n)
{
    const int lane = threadIdx.x & 63;
    const int wave = (int)((blockIdx.x * blockDim.x + threadIdx.x) >> 6);
    if (wave >= n) return;
    const size_t row = (size_t)wave;
    const float* xrow = X + row * (size_t)DIM;
    const float* xf   = xrow + POS;
    const int c3 = cid[row] * 3;
    const float* wp0 = Wp + (size_t)c3 * POS;
    const float* wf0 = Wf + (size_t)c3 * LAT;
    float a0 = 0.f, a1 = 0.f, a2 = 0.f;
#pragma unroll
    for (int i = 0; i < 4; ++i) {
        const int k = lane + 64 * i;
        const float x = xf[k];
        a0 = fmaf(x, wf0[k], a0);
        a1 = fmaf(x, wf0[k + LAT], a1);
        a2 = fmaf(x, wf0[k + 2 * LAT], a2);
    }
    if (lane < POS) {
        const float x = xrow[lane];
        a0 = fmaf(x, wp0[lane], a0);
        a1 = fmaf(x, wp0[lane + POS], a1);
        a2 = fmaf(x, wp0[lane + 2 * POS], a2);
    }
    a0 = wave_reduce_sum(a0);
    a1 = wave_reduce_sum(a1);
    a2 = wave_reduce_sum(a2);
    if (lane == 63) {
        float* o = out + row * 3;
        o[0] = a0; o[1] = a1; o[2] = a2;
    }
}

extern "C" void kernel_launch(void* const* d_in, const int* in_sizes, int n_in,
                              void* d_out, int out_size, void* d_ws, size_t ws_size,
                              hipStream_t stream) {
    const float* X   = (const float*)d_in[0];
    const int*   cid = (const int*)d_in[1];
    const float* Wp  = (const float*)d_in[2];
    const float* Wf  = (const float*)d_in[3];
    float* out = (float*)d_out;
    const int n = in_sizes[1];
    const long nf4 = ((long)n * DIM) / 4;

    if (ws_size >= TB_BYTES && nf4 > 128) {
        uint2* tb = (uint2*)d_ws;
        build_tab<<<(TB_ENTRIES + 255) / 256, 256, 0, stream>>>(Wp, Wf, tb);
        lad_f4<<<NBLK, 256, 0, stream>>>((const float4*)X, cid, tb, out, n, nf4);
    } else {
        const int blocks = (n + 3) / 4;
        lad_fallback<<<blocks, 256, 0, stream>>>(X, cid, Wp, Wf, out, n);
    }
}

// Round 14
// 190.385 us; speedup vs baseline: 1.4730x; 1.2219x over previous
//
#include <hip/hip_runtime.h>

// LinearAutoDecoder R14: dense MFMA per 32-row tile.
// rgb_clusters[32 x 192] = X_tile[32 x 319] @ Wcat^T, then per-row gather of
// the 3 cid-selected channels. Removes the per-row cross-lane reduce (the
// invariant of all prior ~170us kernels) and streams X with the probe-proven
// aligned-float4 slab pattern (6.55 TB/s, R12).
// A/B/C layouts: lane%16 = row(A)/col(B)/col(C) (m89-verified family); any
// consistent K-permutation of A and B fragments is dot-product-invariant.

constexpr int POS = 63, LAT = 256, DIM = 319, NCH = 192;
constexpr int ROWS = 32;                    // rows per tile
constexpr int KPAD = 328;                   // bf16 per LDS X row (bank-friendly)
constexpr int CST  = 196;                   // fp32 per LDS C row
constexpr int PW_DW = NCH * 160;            // 30720 dwords (320 bf16/ch)
constexpr size_t PW_BYTES = (size_t)PW_DW * 4;
constexpr int TILE_F4 = ROWS * DIM / 4;     // 2552 float4 per tile slab
constexpr int NBLK = 2048;

typedef __attribute__((ext_vector_type(8))) short short8;
typedef __attribute__((ext_vector_type(4))) float f32x4;

__device__ __forceinline__ unsigned f2bf(float f) {
    unsigned u = __float_as_uint(f);
    return (u + 0x7fffu + ((u >> 16) & 1u)) >> 16;
}

// pw[ch*160 + d] = bf16(w[ch][2d]) | bf16(w[ch][2d+1])<<16 ; k=319 -> 0
__global__ __launch_bounds__(256) void pack_weights(
    const float* __restrict__ Wp, const float* __restrict__ Wf,
    unsigned* __restrict__ pw)
{
    const int idx = blockIdx.x * 256 + threadIdx.x;
    if (idx >= PW_DW) return;
    const int ch = idx / 160, d = idx - ch * 160;
    auto wat = [&](int k) -> float {
        if (k < POS) return Wp[ch * POS + k];
        if (k < DIM) return Wf[ch * LAT + (k - POS)];
        return 0.f;
    };
    pw[idx] = f2bf(wat(2 * d)) | (f2bf(wat(2 * d + 1)) << 16);
}

__global__ __launch_bounds__(256, 2) void lad_mfma(
    const float4* __restrict__ X4, const int* __restrict__ cid,
    const unsigned* __restrict__ pw, float* __restrict__ out,
    int ntiles, int tpb, long nf4)
{
    __shared__ __align__(16) unsigned short xb[ROWS * KPAD];  // 20,992 B
    __shared__ float cbuf[ROWS * CST];                        // 25,088 B

    const int thr = threadIdx.x;
    const int l   = thr & 63;
    const int wid = thr >> 6;
    const int n0  = wid * 48;        // wave's channel base (4 waves x 48 = 192)
    const int cl  = l & 15;          // row-in-tile (A) / col (B,C)
    const int q   = l >> 4;          // k-quad

    // B fragments: this wave's 48 channels x K=320, held in VGPRs for all tiles.
    short8 Bf[3][10];
#pragma unroll
    for (int nt = 0; nt < 3; ++nt)
#pragma unroll
        for (int kk = 0; kk < 10; ++kk) {
            const unsigned* p = pw + (size_t)(n0 + nt * 16 + cl) * 160
                                   + kk * 16 + q * 4;
            Bf[nt][kk] = *reinterpret_cast<const short8*>(p);
        }

    if (thr < ROWS) xb[thr * KPAD + 319] = 0;   // zero pad col (NaN-safe, persists)

    const int t0 = blockIdx.x * tpb;
    const int tend = min(t0 + tpb, ntiles);
    if (t0 >= tend) return;

    // Prologue: load tile t0's slab (aligned float4, probe pattern).
    float4 xr[10];
    {
        const long b4 = (long)t0 * TILE_F4;
#pragma unroll
        for (int i = 0; i < 10; ++i) {
            long idx = b4 + thr * 10 + i;
            if (idx >= nf4) idx = nf4 - 1;
            xr[i] = X4[idx];
        }
    }

    for (int t = t0; t < tend; ++t) {
        // Gather previous tile's outputs (96 threads; cbuf ready since barrier B).
        if (t > t0 && thr < 96) {
            const int r = thr / 3, j = thr - r * 3;
            const int c = cid[(size_t)(t - 1) * ROWS + r];
            out[((size_t)(t - 1) * ROWS + r) * 3 + j] = cbuf[r * CST + 3 * c + j];
        }

        // Stage tile t: fp32 regs -> bf16 LDS (row = p/319, k = p%319).
        {
            const int p0 = thr * 40;
#pragma unroll
            for (int i = 0; i < 10; ++i) {
                const float4 v = xr[i];
#pragma unroll
                for (int e = 0; e < 4; ++e) {
                    const int p = p0 + i * 4 + e;
                    const float f = (e == 0) ? v.x : (e == 1) ? v.y
                                  : (e == 2) ? v.z : v.w;
                    const int r = (int)((unsigned)p / 319u);
                    if (r < ROWS) {
                        const int k = p - r * 319;
                        xb[r * KPAD + k] = (unsigned short)f2bf(f);
                    }
                }
            }
        }

        // Prefetch tile t+1's slab (lands during MFMA + next barrier).
        if (t + 1 < tend) {
            const long b4 = (long)(t + 1) * TILE_F4;
#pragma unroll
            for (int i = 0; i < 10; ++i) {
                long idx = b4 + thr * 10 + i;
                if (idx >= nf4) idx = nf4 - 1;
                xr[i] = X4[idx];
            }
        }

        __syncthreads();   // barrier A: xb(t) ready; gather(t-1) complete

        // MFMA: this wave computes C[32 x 48] over K=320.
        f32x4 acc[2][3];
#pragma unroll
        for (int mt = 0; mt < 2; ++mt)
#pragma unroll
            for (int nt = 0; nt < 3; ++nt)
                acc[mt][nt] = (f32x4)0.0f;

#pragma unroll
        for (int kk = 0; kk < 10; ++kk) {
            short8 Af[2];
#pragma unroll
            for (int mt = 0; mt < 2; ++mt) {
                const int row = mt * 16 + cl;
                const int k   = kk * 32 + q * 8;
                Af[mt] = *reinterpret_cast<const short8*>(&xb[row * KPAD + k]);
            }
#pragma unroll
            for (int mt = 0; mt < 2; ++mt)
#pragma unroll
                for (int nt = 0; nt < 3; ++nt)
                    acc[mt][nt] = __builtin_amdgcn_mfma_f32_16x16x32_bf16(
                        Af[mt], Bf[nt][kk], acc[mt][nt], 0, 0, 0);
        }

        // C -> LDS (col = lane&15, row = (lane>>4)*4 + reg; m89-verified).
#pragma unroll
        for (int mt = 0; mt < 2; ++mt)
#pragma unroll
            for (int nt = 0; nt < 3; ++nt)
#pragma unroll
                for (int j = 0; j < 4; ++j) {
                    const int row = mt * 16 + q * 4 + j;
                    const int col = n0 + nt * 16 + cl;
                    cbuf[row * CST + col] = acc[mt][nt][j];
                }

        __syncthreads();   // barrier B: cbuf(t) ready; xb free for next stage
    }

    // Final gather.
    if (thr < 96) {
        const int t = tend - 1;
        const int r = thr / 3, j = thr - r * 3;
        const int c = cid[(size_t)t * ROWS + r];
        out[((size_t)t * ROWS + r) * 3 + j] = cbuf[r * CST + 3 * c + j];
    }
}

// ---------- fallback (R2-style, fp32 weights, no workspace) ----------
template <int CTRL>
__device__ __forceinline__ float dpp_add_step(float x) {
    int s = __builtin_amdgcn_update_dpp(0, __float_as_int(x), CTRL,
                                        0xF, 0xF, true);
    return x + __int_as_float(s);
}
__device__ __forceinline__ float wave_reduce_sum(float x) {
    x = dpp_add_step<0x111>(x);
    x = dpp_add_step<0x112>(x);
    x = dpp_add_step<0x114>(x);
    x = dpp_add_step<0x118>(x);
    x = dpp_add_step<0x142>(x);
    x = dpp_add_step<0x143>(x);
    return x;   // lane 63
}

__global__ __launch_bounds__(256) void lad_fallback(
    const float* __restrict__ X, const int* __restrict__ cid,
    const float* __restrict__ Wp, const float* __restrict__ Wf,
    float* __restrict__ out, int n)
{
    const int lane = threadIdx.x & 63;
    const int wave = (int)((blockIdx.x * blockDim.x + threadIdx.x) >> 6);
    if (wave >= n) return;
    const size_t row = (size_t)wave;
    const float* xrow = X + row * (size_t)DIM;
    const float* xf   = xrow + POS;
    const int c3 = cid[row] * 3;
    const float* wp0 = Wp + (size_t)c3 * POS;
    const float* wf0 = Wf + (size_t)c3 * LAT;
    float a0 = 0.f, a1 = 0.f, a2 = 0.f;
#pragma unroll
    for (int i = 0; i < 4; ++i) {
        const int k = lane + 64 * i;
        const float x = xf[k];
        a0 = fmaf(x, wf0[k], a0);
        a1 = fmaf(x, wf0[k + LAT], a1);
        a2 = fmaf(x, wf0[k + 2 * LAT], a2);
    }
    if (lane < POS) {
        const float x = xrow[lane];
        a0 = fmaf(x, wp0[lane], a0);
        a1 = fmaf(x, wp0[lane + POS], a1);
        a2 = fmaf(x, wp0[lane + 2 * POS], a2);
    }
    a0 = wave_reduce_sum(a0);
    a1 = wave_reduce_sum(a1);
    a2 = wave_reduce_sum(a2);
    if (lane == 63) {
        float* o = out + row * 3;
        o[0] = a0; o[1] = a1; o[2] = a2;
    }
}

extern "C" void kernel_launch(void* const* d_in, const int* in_sizes, int n_in,
                              void* d_out, int out_size, void* d_ws, size_t ws_size,
                              hipStream_t stream) {
    const float* X   = (const float*)d_in[0];
    const int*   cid = (const int*)d_in[1];
    const float* Wp  = (const float*)d_in[2];
    const float* Wf  = (const float*)d_in[3];
    float* out = (float*)d_out;
    const int n = in_sizes[1];

    if (ws_size >= PW_BYTES && n > 0 && (n % ROWS) == 0) {
        unsigned* pw = (unsigned*)d_ws;
        pack_weights<<<(PW_DW + 255) / 256, 256, 0, stream>>>(Wp, Wf, pw);
        const int ntiles = n / ROWS;                       // 16384
        const int tpb = (ntiles + NBLK - 1) / NBLK;        // 8
        const int grid = (ntiles + tpb - 1) / tpb;         // 2048
        const long nf4 = (long)n * DIM / 4;
        lad_mfma<<<grid, 256, 0, stream>>>((const float4*)X, cid, pw, out,
                                           ntiles, tpb, nf4);
    } else {
        const int blocks = (n + 3) / 4;
        lad_fallback<<<blocks, 256, 0, stream>>>(X, cid, Wp, Wf, out, n);
    }
}